// Round 1
// baseline (3354.155 us; speedup 1.0000x reference)
//
#include <hip/hip_runtime.h>
#include <hip/hip_bf16.h>

// GraphSAGE 2-layer forward, fp32.
//   layer l: h = BN_l( mean_agg(h_in) @ Wl_l^T + h_in @ Wr_l^T + b_l ); ReLU after layer 0.
// Aggregation: scatter-atomic (coalesced float4 rows, 4x global_atomic_add_f32).
// GEMM: 32-node x 128-col tile per 256-thread block, K chunked by 32 via LDS.

#define D 128
#define NT 32      // nodes per GEMM block
#define KC 32      // K chunk

__global__ __launch_bounds__(256)
void scatter_kernel(const float* __restrict__ xin, const int* __restrict__ src,
                    const int* __restrict__ dst, float* __restrict__ agg,
                    float* __restrict__ cnt, int E, int do_cnt)
{
    int tid = blockIdx.x * 256 + threadIdx.x;
    int e = tid >> 5;                 // 32 threads per edge
    if (e >= E) return;
    int lane4 = (tid & 31) * 4;      // 4 floats per thread
    int s = src[e];
    int d = dst[e];
    const float4 v = *reinterpret_cast<const float4*>(xin + s * D + lane4);
    float* p = agg + d * D + lane4;
    unsafeAtomicAdd(p + 0, v.x);
    unsafeAtomicAdd(p + 1, v.y);
    unsafeAtomicAdd(p + 2, v.z);
    unsafeAtomicAdd(p + 3, v.w);
    if (do_cnt && (tid & 31) == 0) unsafeAtomicAdd(cnt + d, 1.0f);
}

__global__ __launch_bounds__(256)
void invcnt_kernel(const float* __restrict__ cnt, float* __restrict__ inv, int Nn)
{
    int n = blockIdx.x * 256 + threadIdx.x;
    if (n < Nn) inv[n] = 1.0f / fmaxf(cnt[n], 1.0f);
}

// out[n,j] = BN( sum_k agg[n,k]*inv[n]*Wl[j,k] + xin[n,k]*Wr[j,k] + b[j] ), optional ReLU
__global__ __launch_bounds__(256)
void gemm_bn_kernel(const float* __restrict__ agg, const float* __restrict__ inv,
                    const float* __restrict__ xin,
                    const float* __restrict__ Wl, const float* __restrict__ Wr,
                    const float* __restrict__ bias,
                    const float* __restrict__ gamma, const float* __restrict__ beta,
                    const float* __restrict__ rmean, const float* __restrict__ rvar,
                    float* __restrict__ out, int relu, int Nn)
{
    __shared__ float swl[D][KC + 1];   // +1 pad: weight reads 2-way bank alias (free)
    __shared__ float swr[D][KC + 1];
    __shared__ float sa[NT][KC + 1];
    __shared__ float sx[NT][KC + 1];

    const int tid = threadIdx.x;
    const int j = tid & 127;          // output column
    const int nhalf = tid >> 7;       // 0/1 -> node half
    const int nb = blockIdx.x * NT;

    float acc[16];
#pragma unroll
    for (int i = 0; i < 16; ++i) acc[i] = 0.f;

    for (int k0 = 0; k0 < D; k0 += KC) {
        const int kk = tid & 31;
        const int r  = tid >> 5;      // 0..7
        // stage weights: 128 rows x KC cols each
#pragma unroll
        for (int it = 0; it < 16; ++it) {
            int jj = it * 8 + r;
            swl[jj][kk] = Wl[jj * D + k0 + kk];
            swr[jj][kk] = Wr[jj * D + k0 + kk];
        }
        // stage inputs: NT rows x KC cols (normalize agg on the fly)
#pragma unroll
        for (int it = 0; it < 4; ++it) {
            int nn = it * 8 + r;
            int n = nb + nn;
            float a = 0.f, xv = 0.f;
            if (n < Nn) {
                a  = agg[n * D + k0 + kk] * inv[n];
                xv = xin[n * D + k0 + kk];
            }
            sa[nn][kk] = a;
            sx[nn][kk] = xv;
        }
        __syncthreads();

        const int n0 = nhalf * 16;
#pragma unroll
        for (int kkk = 0; kkk < KC; ++kkk) {
            float wl = swl[j][kkk];
            float wr = swr[j][kkk];
#pragma unroll
            for (int i = 0; i < 16; ++i) {
                acc[i] += sa[n0 + i][kkk] * wl + sx[n0 + i][kkk] * wr;
            }
        }
        __syncthreads();
    }

    // fused bias + BN(eval) + optional ReLU
    const float scale = gamma[j] * rsqrtf(rvar[j] + 1e-5f);
    const float shift = beta[j] - rmean[j] * scale;
    const float bj = bias[j];
    const int n0 = nhalf * 16;
#pragma unroll
    for (int i = 0; i < 16; ++i) {
        int n = nb + n0 + i;
        if (n < Nn) {
            float v = (acc[i] + bj) * scale + shift;
            if (relu) v = fmaxf(v, 0.f);
            out[n * D + j] = v;
        }
    }
}

extern "C" void kernel_launch(void* const* d_in, const int* in_sizes, int n_in,
                              void* d_out, int out_size, void* d_ws, size_t ws_size,
                              hipStream_t stream)
{
    const float* x   = (const float*)d_in[0];
    const int*   ei  = (const int*)d_in[1];
    const float* Wl0 = (const float*)d_in[2];
    const float* Wr0 = (const float*)d_in[3];
    const float* b0  = (const float*)d_in[4];
    const float* g0  = (const float*)d_in[5];
    const float* be0 = (const float*)d_in[6];
    const float* rm0 = (const float*)d_in[7];
    const float* rv0 = (const float*)d_in[8];
    const float* Wl1 = (const float*)d_in[9];
    const float* Wr1 = (const float*)d_in[10];
    const float* b1  = (const float*)d_in[11];
    const float* g1  = (const float*)d_in[12];
    const float* be1 = (const float*)d_in[13];
    const float* rm1 = (const float*)d_in[14];
    const float* rv1 = (const float*)d_in[15];

    const int N = in_sizes[0] / D;
    const int E = in_sizes[1] / 2;
    const int* src = ei;
    const int* dst = ei + E;

    // workspace layout (floats): agg[N*D] | cnt[N] | inv[N] | h0[N*D]
    float* agg = (float*)d_ws;
    float* cnt = agg + (size_t)N * D;
    float* inv = cnt + N;
    float* h0  = inv + N;

    float* out = (float*)d_out;

    const int scatter_blocks = (E * 32 + 255) / 256;
    const int gemm_blocks = (N + NT - 1) / NT;

    // ---- layer 0 ----
    hipMemsetAsync(agg, 0, sizeof(float) * ((size_t)N * D + N), stream);  // agg + cnt
    scatter_kernel<<<scatter_blocks, 256, 0, stream>>>(x, src, dst, agg, cnt, E, 1);
    invcnt_kernel<<<(N + 255) / 256, 256, 0, stream>>>(cnt, inv, N);
    gemm_bn_kernel<<<gemm_blocks, 256, 0, stream>>>(agg, inv, x, Wl0, Wr0, b0,
                                                    g0, be0, rm0, rv0, h0, 1, N);
    // ---- layer 1 ----
    hipMemsetAsync(agg, 0, sizeof(float) * (size_t)N * D, stream);
    scatter_kernel<<<scatter_blocks, 256, 0, stream>>>(h0, src, dst, agg, cnt, E, 0);
    gemm_bn_kernel<<<gemm_blocks, 256, 0, stream>>>(agg, inv, h0, Wl1, Wr1, b1,
                                                    g1, be1, rm1, rv1, out, 0, N);
}

// Round 3
// 804.166 us; speedup vs baseline: 4.1710x; 4.1710x over previous
//
#include <hip/hip_runtime.h>
#include <hip/hip_bf16.h>

// GraphSAGE 2-layer forward, fp32.
//   layer l: h = BN_l( mean_agg(h_in) @ Wl_l^T + h_in @ Wr_l^T + b_l ); ReLU after layer 0.
// Round 1: CSR-by-dst build (once per launch) + gather-mean aggregation
//          (replaces 102M fp32 global atomics per layer -> was 2x1380us, atomic-bound).
// Round 2: unchanged resubmit (round-1 bench hit GPUAcquisitionTimeout; need the measurement).

#define D 128
#define NT 32      // nodes per GEMM block
#define KC 32      // K chunk

// ---------- CSR build ----------

__global__ __launch_bounds__(256)
void hist_kernel(const int* __restrict__ dst, int* __restrict__ cnt, int E)
{
    int e = blockIdx.x * 256 + threadIdx.x;
    if (e < E) atomicAdd(&cnt[dst[e]], 1);
}

// exclusive block-scan; emits per-block sums; also emits inv = 1/max(cnt,1)
__global__ __launch_bounds__(256)
void scan1_kernel(const int* __restrict__ cnt, int* __restrict__ rowptr,
                  int* __restrict__ bsum, float* __restrict__ inv, int Nn)
{
    __shared__ int s[256];
    const int tid = threadIdx.x;
    const int g = blockIdx.x * 256 + tid;
    int v = (g < Nn) ? cnt[g] : 0;
    if (g < Nn) inv[g] = 1.0f / fmaxf((float)v, 1.0f);
    s[tid] = v;
    __syncthreads();
    for (int off = 1; off < 256; off <<= 1) {
        int t = (tid >= off) ? s[tid - off] : 0;
        __syncthreads();
        s[tid] += t;
        __syncthreads();
    }
    if (g < Nn) rowptr[g] = s[tid] - v;              // exclusive
    if (tid == 255) bsum[blockIdx.x] = s[255];
}

__global__ __launch_bounds__(256)
void scan2_kernel(int* __restrict__ bsum, int nb)
{
    __shared__ int s[256];
    const int tid = threadIdx.x;
    int v = (tid < nb) ? bsum[tid] : 0;
    s[tid] = v;
    __syncthreads();
    for (int off = 1; off < 256; off <<= 1) {
        int t = (tid >= off) ? s[tid - off] : 0;
        __syncthreads();
        s[tid] += t;
        __syncthreads();
    }
    if (tid < nb) bsum[tid] = s[tid] - v;            // exclusive
}

__global__ __launch_bounds__(256)
void scan3_kernel(int* __restrict__ rowptr, int* __restrict__ cursor,
                  const int* __restrict__ bsum, int Nn, int E)
{
    const int g = blockIdx.x * 256 + threadIdx.x;
    if (g < Nn) {
        int v = rowptr[g] + bsum[blockIdx.x];
        rowptr[g] = v;
        cursor[g] = v;
    }
    if (g == 0) rowptr[Nn] = E;
}

__global__ __launch_bounds__(256)
void fill_kernel(const int* __restrict__ src, const int* __restrict__ dst,
                 int* __restrict__ cursor, int* __restrict__ adj, int E)
{
    int e = blockIdx.x * 256 + threadIdx.x;
    if (e < E) {
        int pos = atomicAdd(&cursor[dst[e]], 1);
        adj[pos] = src[e];
    }
}

// ---------- gather-mean aggregation: one wave per node ----------

__global__ __launch_bounds__(256)
void gather_kernel(const float* __restrict__ xin, const int* __restrict__ rowptr,
                   const int* __restrict__ adj, const float* __restrict__ inv,
                   float* __restrict__ agg, int Nn)
{
    const int gwid = (blockIdx.x * 256 + threadIdx.x) >> 6;   // one wave per node
    const int lane = threadIdx.x & 63;
    if (gwid >= Nn) return;
    const int beg = rowptr[gwid];
    const int end = rowptr[gwid + 1];
    float ax = 0.f, ay = 0.f;
    int i = beg;
    for (; i + 1 < end; i += 2) {        // unroll-2 for load pipelining
        int s0 = adj[i], s1 = adj[i + 1];
        float2 v0 = *reinterpret_cast<const float2*>(xin + s0 * D + lane * 2);
        float2 v1 = *reinterpret_cast<const float2*>(xin + s1 * D + lane * 2);
        ax += v0.x + v1.x;
        ay += v0.y + v1.y;
    }
    if (i < end) {
        int s0 = adj[i];
        float2 v0 = *reinterpret_cast<const float2*>(xin + s0 * D + lane * 2);
        ax += v0.x;
        ay += v0.y;
    }
    const float sc = inv[gwid];
    *reinterpret_cast<float2*>(agg + (size_t)gwid * D + lane * 2) =
        make_float2(ax * sc, ay * sc);
}

// ---------- GEMM + BN epilogue ----------
// out[n,j] = BN( sum_k agg[n,k]*Wl[j,k] + xin[n,k]*Wr[j,k] + b[j] ), optional ReLU
// (agg arrives pre-normalized)
__global__ __launch_bounds__(256)
void gemm_bn_kernel(const float* __restrict__ agg,
                    const float* __restrict__ xin,
                    const float* __restrict__ Wl, const float* __restrict__ Wr,
                    const float* __restrict__ bias,
                    const float* __restrict__ gamma, const float* __restrict__ beta,
                    const float* __restrict__ rmean, const float* __restrict__ rvar,
                    float* __restrict__ out, int relu, int Nn)
{
    __shared__ float swl[D][KC + 1];
    __shared__ float swr[D][KC + 1];
    __shared__ float sa[NT][KC + 1];
    __shared__ float sx[NT][KC + 1];

    const int tid = threadIdx.x;
    const int j = tid & 127;
    const int nhalf = tid >> 7;
    const int nb = blockIdx.x * NT;

    float acc[16];
#pragma unroll
    for (int i = 0; i < 16; ++i) acc[i] = 0.f;

    for (int k0 = 0; k0 < D; k0 += KC) {
        const int kk = tid & 31;
        const int r  = tid >> 5;
#pragma unroll
        for (int it = 0; it < 16; ++it) {
            int jj = it * 8 + r;
            swl[jj][kk] = Wl[jj * D + k0 + kk];
            swr[jj][kk] = Wr[jj * D + k0 + kk];
        }
#pragma unroll
        for (int it = 0; it < 4; ++it) {
            int nn = it * 8 + r;
            int n = nb + nn;
            float a = 0.f, xv = 0.f;
            if (n < Nn) {
                a  = agg[n * D + k0 + kk];
                xv = xin[n * D + k0 + kk];
            }
            sa[nn][kk] = a;
            sx[nn][kk] = xv;
        }
        __syncthreads();

        const int n0 = nhalf * 16;
#pragma unroll
        for (int kkk = 0; kkk < KC; ++kkk) {
            float wl = swl[j][kkk];
            float wr = swr[j][kkk];
#pragma unroll
            for (int i = 0; i < 16; ++i) {
                acc[i] += sa[n0 + i][kkk] * wl + sx[n0 + i][kkk] * wr;
            }
        }
        __syncthreads();
    }

    const float scale = gamma[j] * rsqrtf(rvar[j] + 1e-5f);
    const float shift = beta[j] - rmean[j] * scale;
    const float bj = bias[j];
    const int n0 = nhalf * 16;
#pragma unroll
    for (int i = 0; i < 16; ++i) {
        int n = nb + n0 + i;
        if (n < Nn) {
            float v = (acc[i] + bj) * scale + shift;
            if (relu) v = fmaxf(v, 0.f);
            out[n * D + j] = v;
        }
    }
}

extern "C" void kernel_launch(void* const* d_in, const int* in_sizes, int n_in,
                              void* d_out, int out_size, void* d_ws, size_t ws_size,
                              hipStream_t stream)
{
    const float* x   = (const float*)d_in[0];
    const int*   ei  = (const int*)d_in[1];
    const float* Wl0 = (const float*)d_in[2];
    const float* Wr0 = (const float*)d_in[3];
    const float* b0  = (const float*)d_in[4];
    const float* g0  = (const float*)d_in[5];
    const float* be0 = (const float*)d_in[6];
    const float* rm0 = (const float*)d_in[7];
    const float* rv0 = (const float*)d_in[8];
    const float* Wl1 = (const float*)d_in[9];
    const float* Wr1 = (const float*)d_in[10];
    const float* b1  = (const float*)d_in[11];
    const float* g1  = (const float*)d_in[12];
    const float* be1 = (const float*)d_in[13];
    const float* rm1 = (const float*)d_in[14];
    const float* rv1 = (const float*)d_in[15];

    const int N = in_sizes[0] / D;
    const int E = in_sizes[1] / 2;
    const int* src = ei;
    const int* dst = ei + E;

    // workspace layout: agg f[N*D] | h0 f[N*D] | inv f[N] | cnt i[N] |
    //                   rowptr i[N+1] | cursor i[N] | bsum i[256] | adj i[E]
    float* agg    = (float*)d_ws;
    float* h0     = agg + (size_t)N * D;
    float* inv    = h0 + (size_t)N * D;
    int*   cnt    = (int*)(inv + N);
    int*   rowptr = cnt + N;
    int*   cursor = rowptr + (N + 1);
    int*   bsum   = cursor + N;
    int*   adj    = bsum + 256;

    float* out = (float*)d_out;

    const int eblocks = (E + 255) / 256;
    const int nblocks = (N + 255) / 256;
    const int gemm_blocks = (N + NT - 1) / NT;
    const int gather_blocks = (N * 64 + 255) / 256;   // one wave per node

    // ---- CSR build (shared by both layers) ----
    hipMemsetAsync(cnt, 0, sizeof(int) * N, stream);
    hist_kernel<<<eblocks, 256, 0, stream>>>(dst, cnt, E);
    scan1_kernel<<<nblocks, 256, 0, stream>>>(cnt, rowptr, bsum, inv, N);
    scan2_kernel<<<1, 256, 0, stream>>>(bsum, nblocks);
    scan3_kernel<<<nblocks, 256, 0, stream>>>(rowptr, cursor, bsum, N, E);
    fill_kernel<<<eblocks, 256, 0, stream>>>(src, dst, cursor, adj, E);

    // ---- layer 0 ----
    gather_kernel<<<gather_blocks, 256, 0, stream>>>(x, rowptr, adj, inv, agg, N);
    gemm_bn_kernel<<<gemm_blocks, 256, 0, stream>>>(agg, x, Wl0, Wr0, b0,
                                                    g0, be0, rm0, rv0, h0, 1, N);
    // ---- layer 1 ----
    gather_kernel<<<gather_blocks, 256, 0, stream>>>(h0, rowptr, adj, inv, agg, N);
    gemm_bn_kernel<<<gemm_blocks, 256, 0, stream>>>(agg, h0, Wl1, Wr1, b1,
                                                    g1, be1, rm1, rv1, out, 0, N);
}

// Round 5
// 428.203 us; speedup vs baseline: 7.8331x; 1.8780x over previous
//
#include <hip/hip_runtime.h>
#include <hip/hip_bf16.h>

// GraphSAGE 2-layer forward, fp32.
//   layer l: h = BN_l( mean_agg(h_in) @ Wl_l^T + h_in @ Wr_l^T + b_l ); ReLU after layer 0.
// Round 1: CSR-by-dst build + gather-mean aggregation (killed fp32 atomics; 3354 -> 804us).
// Round 3: register-tiled GEMM. Old inner loop was 34 scalar ds_read per 32 FMA
//          (VALUBusy 27%, LDS-issue bound). New: 4x8 thread tile, transposed LDS
//          tiles, 3 ds_read_b128 per 32 FMA -> FMA-bound.
// Round 4: unchanged resubmit (round-3 bench hit GPUAcquisitionTimeout).

#define D 128
#define BM 64      // nodes per GEMM block
#define BK 32      // K chunk

// ---------- CSR build ----------

__global__ __launch_bounds__(256)
void hist_kernel(const int* __restrict__ dst, int* __restrict__ cnt, int E)
{
    int e = blockIdx.x * 256 + threadIdx.x;
    if (e < E) atomicAdd(&cnt[dst[e]], 1);
}

// exclusive block-scan; emits per-block sums; also emits inv = 1/max(cnt,1)
__global__ __launch_bounds__(256)
void scan1_kernel(const int* __restrict__ cnt, int* __restrict__ rowptr,
                  int* __restrict__ bsum, float* __restrict__ inv, int Nn)
{
    __shared__ int s[256];
    const int tid = threadIdx.x;
    const int g = blockIdx.x * 256 + tid;
    int v = (g < Nn) ? cnt[g] : 0;
    if (g < Nn) inv[g] = 1.0f / fmaxf((float)v, 1.0f);
    s[tid] = v;
    __syncthreads();
    for (int off = 1; off < 256; off <<= 1) {
        int t = (tid >= off) ? s[tid - off] : 0;
        __syncthreads();
        s[tid] += t;
        __syncthreads();
    }
    if (g < Nn) rowptr[g] = s[tid] - v;              // exclusive
    if (tid == 255) bsum[blockIdx.x] = s[255];
}

__global__ __launch_bounds__(256)
void scan2_kernel(int* __restrict__ bsum, int nb)
{
    __shared__ int s[256];
    const int tid = threadIdx.x;
    int v = (tid < nb) ? bsum[tid] : 0;
    s[tid] = v;
    __syncthreads();
    for (int off = 1; off < 256; off <<= 1) {
        int t = (tid >= off) ? s[tid - off] : 0;
        __syncthreads();
        s[tid] += t;
        __syncthreads();
    }
    if (tid < nb) bsum[tid] = s[tid] - v;            // exclusive
}

__global__ __launch_bounds__(256)
void scan3_kernel(int* __restrict__ rowptr, int* __restrict__ cursor,
                  const int* __restrict__ bsum, int Nn, int E)
{
    const int g = blockIdx.x * 256 + threadIdx.x;
    if (g < Nn) {
        int v = rowptr[g] + bsum[blockIdx.x];
        rowptr[g] = v;
        cursor[g] = v;
    }
    if (g == 0) rowptr[Nn] = E;
}

__global__ __launch_bounds__(256)
void fill_kernel(const int* __restrict__ src, const int* __restrict__ dst,
                 int* __restrict__ cursor, int* __restrict__ adj, int E)
{
    int e = blockIdx.x * 256 + threadIdx.x;
    if (e < E) {
        int pos = atomicAdd(&cursor[dst[e]], 1);
        adj[pos] = src[e];
    }
}

// ---------- gather-mean aggregation: one wave per node ----------

__global__ __launch_bounds__(256)
void gather_kernel(const float* __restrict__ xin, const int* __restrict__ rowptr,
                   const int* __restrict__ adj, const float* __restrict__ inv,
                   float* __restrict__ agg, int Nn)
{
    const int gwid = (blockIdx.x * 256 + threadIdx.x) >> 6;   // one wave per node
    const int lane = threadIdx.x & 63;
    if (gwid >= Nn) return;
    const int beg = rowptr[gwid];
    const int end = rowptr[gwid + 1];
    float ax = 0.f, ay = 0.f;
    int i = beg;
    for (; i + 1 < end; i += 2) {        // unroll-2 for load pipelining
        int s0 = adj[i], s1 = adj[i + 1];
        float2 v0 = *reinterpret_cast<const float2*>(xin + s0 * D + lane * 2);
        float2 v1 = *reinterpret_cast<const float2*>(xin + s1 * D + lane * 2);
        ax += v0.x + v1.x;
        ay += v0.y + v1.y;
    }
    if (i < end) {
        int s0 = adj[i];
        float2 v0 = *reinterpret_cast<const float2*>(xin + s0 * D + lane * 2);
        ax += v0.x;
        ay += v0.y;
    }
    const float sc = inv[gwid];
    *reinterpret_cast<float2*>(agg + (size_t)gwid * D + lane * 2) =
        make_float2(ax * sc, ay * sc);
}

// ---------- register-tiled GEMM + BN epilogue ----------
// out[n,j] = BN( sum_k agg[n,k]*Wl[j,k] + xin[n,k]*Wr[j,k] + b[j] ), optional ReLU.
// Block: 64 nodes x 128 cols, 256 threads, thread tile 4n x 8j.
// LDS tiles transposed: saT[k][n], swT[k][j] -> inner loop is 3x ds_read_b128
// (one A-float4, two W-float4) per 32 FMAs.
__global__ __launch_bounds__(256)
void gemm_bn_kernel(const float* __restrict__ agg,
                    const float* __restrict__ xin,
                    const float* __restrict__ Wl, const float* __restrict__ Wr,
                    const float* __restrict__ bias,
                    const float* __restrict__ gamma, const float* __restrict__ beta,
                    const float* __restrict__ rmean, const float* __restrict__ rvar,
                    float* __restrict__ out, int relu, int Nn)
{
    __shared__ float saT[BK][BM + 4];   // [k][n], row = 68 floats (16B-aligned, 2-way max)
    __shared__ float swT[BK][D + 4];    // [k][j], row = 132 floats

    const int tid = threadIdx.x;
    const int tn = tid & 15;            // node group: nodes tn*4 .. tn*4+3
    const int tj = tid >> 4;            // col group:  cols  tj*8 .. tj*8+7
    const int nb = blockIdx.x * BM;

    float acc[4][8];
#pragma unroll
    for (int i = 0; i < 4; ++i)
#pragma unroll
        for (int jj = 0; jj < 8; ++jj) acc[i][jj] = 0.f;

    for (int pass = 0; pass < 2; ++pass) {
        const float* __restrict__ A = pass ? xin : agg;
        const float* __restrict__ W = pass ? Wr : Wl;

        for (int k0 = 0; k0 < D; k0 += BK) {
            // stage A chunk transposed: 64n x 32k = 512 float4, 2 per thread
#pragma unroll
            for (int it = 0; it < 2; ++it) {
                int lin = it * 256 + tid;
                int n = lin >> 3;              // 0..63
                int kq = (lin & 7) * 4;        // 0,4,..,28
                int gn = nb + n;
                float4 v = make_float4(0.f, 0.f, 0.f, 0.f);
                if (gn < Nn)
                    v = *reinterpret_cast<const float4*>(A + (size_t)gn * D + k0 + kq);
                saT[kq + 0][n] = v.x;
                saT[kq + 1][n] = v.y;
                saT[kq + 2][n] = v.z;
                saT[kq + 3][n] = v.w;
            }
            // stage W chunk transposed: 128j x 32k = 1024 float4, 4 per thread
#pragma unroll
            for (int it = 0; it < 4; ++it) {
                int lin = it * 256 + tid;
                int j = lin >> 3;              // 0..127
                int kq = (lin & 7) * 4;
                float4 w = *reinterpret_cast<const float4*>(W + j * D + k0 + kq);
                swT[kq + 0][j] = w.x;
                swT[kq + 1][j] = w.y;
                swT[kq + 2][j] = w.z;
                swT[kq + 3][j] = w.w;
            }
            __syncthreads();

#pragma unroll 8
            for (int kk = 0; kk < BK; ++kk) {
                const float4 a  = *reinterpret_cast<const float4*>(&saT[kk][tn * 4]);
                const float4 w0 = *reinterpret_cast<const float4*>(&swT[kk][tj * 8]);
                const float4 w1 = *reinterpret_cast<const float4*>(&swT[kk][tj * 8 + 4]);
                const float av[4] = {a.x, a.y, a.z, a.w};
                const float wv[8] = {w0.x, w0.y, w0.z, w0.w, w1.x, w1.y, w1.z, w1.w};
#pragma unroll
                for (int i = 0; i < 4; ++i)
#pragma unroll
                    for (int jj = 0; jj < 8; ++jj)
                        acc[i][jj] += av[i] * wv[jj];
            }
            __syncthreads();
        }
    }

    // fused bias + BN(eval) + optional ReLU, float4 stores
    const int jb = tj * 8;
    float scale[8], shift[8];
#pragma unroll
    for (int jj = 0; jj < 8; ++jj) {
        int j = jb + jj;
        float sc = gamma[j] * rsqrtf(rvar[j] + 1e-5f);
        scale[jj] = sc;
        shift[jj] = bias[j] * sc + beta[j] - rmean[j] * sc;
    }
#pragma unroll
    for (int i = 0; i < 4; ++i) {
        int n = nb + tn * 4 + i;
        if (n < Nn) {
            float v[8];
#pragma unroll
            for (int jj = 0; jj < 8; ++jj) {
                v[jj] = acc[i][jj] * scale[jj] + shift[jj];
                if (relu) v[jj] = fmaxf(v[jj], 0.f);
            }
            float* po = out + (size_t)n * D + jb;
            *reinterpret_cast<float4*>(po)     = make_float4(v[0], v[1], v[2], v[3]);
            *reinterpret_cast<float4*>(po + 4) = make_float4(v[4], v[5], v[6], v[7]);
        }
    }
}

extern "C" void kernel_launch(void* const* d_in, const int* in_sizes, int n_in,
                              void* d_out, int out_size, void* d_ws, size_t ws_size,
                              hipStream_t stream)
{
    const float* x   = (const float*)d_in[0];
    const int*   ei  = (const int*)d_in[1];
    const float* Wl0 = (const float*)d_in[2];
    const float* Wr0 = (const float*)d_in[3];
    const float* b0  = (const float*)d_in[4];
    const float* g0  = (const float*)d_in[5];
    const float* be0 = (const float*)d_in[6];
    const float* rm0 = (const float*)d_in[7];
    const float* rv0 = (const float*)d_in[8];
    const float* Wl1 = (const float*)d_in[9];
    const float* Wr1 = (const float*)d_in[10];
    const float* b1  = (const float*)d_in[11];
    const float* g1  = (const float*)d_in[12];
    const float* be1 = (const float*)d_in[13];
    const float* rm1 = (const float*)d_in[14];
    const float* rv1 = (const float*)d_in[15];

    const int N = in_sizes[0] / D;
    const int E = in_sizes[1] / 2;
    const int* src = ei;
    const int* dst = ei + E;

    // workspace layout: agg f[N*D] | h0 f[N*D] | inv f[N] | cnt i[N] |
    //                   rowptr i[N+1] | cursor i[N] | bsum i[256] | adj i[E]
    float* agg    = (float*)d_ws;
    float* h0     = agg + (size_t)N * D;
    float* inv    = h0 + (size_t)N * D;
    int*   cnt    = (int*)(inv + N);
    int*   rowptr = cnt + N;
    int*   cursor = rowptr + (N + 1);
    int*   bsum   = cursor + N;
    int*   adj    = bsum + 256;

    float* out = (float*)d_out;

    const int eblocks = (E + 255) / 256;
    const int nblocks = (N + 255) / 256;
    const int gemm_blocks = (N + BM - 1) / BM;
    const int gather_blocks = (N * 64 + 255) / 256;   // one wave per node

    // ---- CSR build (shared by both layers) ----
    hipMemsetAsync(cnt, 0, sizeof(int) * N, stream);
    hist_kernel<<<eblocks, 256, 0, stream>>>(dst, cnt, E);
    scan1_kernel<<<nblocks, 256, 0, stream>>>(cnt, rowptr, bsum, inv, N);
    scan2_kernel<<<1, 256, 0, stream>>>(bsum, nblocks);
    scan3_kernel<<<nblocks, 256, 0, stream>>>(rowptr, cursor, bsum, N, E);
    fill_kernel<<<eblocks, 256, 0, stream>>>(src, dst, cursor, adj, E);

    // ---- layer 0 ----
    gather_kernel<<<gather_blocks, 256, 0, stream>>>(x, rowptr, adj, inv, agg, N);
    gemm_bn_kernel<<<gemm_blocks, 256, 0, stream>>>(agg, x, Wl0, Wr0, b0,
                                                    g0, be0, rm0, rv0, h0, 1, N);
    // ---- layer 1 ----
    gather_kernel<<<gather_blocks, 256, 0, stream>>>(h0, rowptr, adj, inv, agg, N);
    gemm_bn_kernel<<<gemm_blocks, 256, 0, stream>>>(agg, h0, Wl1, Wr1, b1,
                                                    g1, be1, rm1, rv1, out, 0, N);
}

// Round 8
// 333.556 us; speedup vs baseline: 10.0558x; 1.2838x over previous
//
#include <hip/hip_runtime.h>
#include <hip/hip_bf16.h>

// GraphSAGE 2-layer forward.
//   layer l: h = BN_l( mean_agg(h_in) @ Wl_l^T + h_in @ Wr_l^T + b_l ); ReLU after layer 0.
// Round 1: CSR-by-dst build + gather-mean aggregation (killed fp32 atomics; 3354 -> 804us).
// Round 3: register-tiled fp32 GEMM (804 -> 428us; gemm 266 -> 70us).
// Round 5: bf16 everywhere internally (threshold 1.13e-1 is bf16-scale):
//          - gather reads/writes bf16 (halves the 410MB/layer cache traffic)
//          - GEMM via mfma_f32_16x16x32_bf16, XOR-swizzled LDS (T2), fp32 accum,
//            both passes into one accumulator, BN fused in epilogue.
// Rounds 6-7: unchanged resubmits (GPUAcquisitionTimeout both rounds).

#define D 128
#define BM 64

typedef __attribute__((ext_vector_type(8))) short short8;   // 8 bf16 (4 VGPRs)
typedef __attribute__((ext_vector_type(4))) float f32x4;

__device__ inline uint f2bf(float f) {   // fp32 -> bf16 bits, round-to-nearest-even
    uint u = __float_as_uint(f);
    return (u + 0x7fffu + ((u >> 16) & 1u)) >> 16;
}

// ---------- dtype conversion ----------
__global__ __launch_bounds__(256)
void convert_f2b_kernel(const float* __restrict__ in, ushort* __restrict__ out, int n4)
{
    int i = blockIdx.x * 256 + threadIdx.x;
    if (i < n4) {
        float4 v = reinterpret_cast<const float4*>(in)[i];
        ushort4 o;
        o.x = (ushort)f2bf(v.x);
        o.y = (ushort)f2bf(v.y);
        o.z = (ushort)f2bf(v.z);
        o.w = (ushort)f2bf(v.w);
        reinterpret_cast<ushort4*>(out)[i] = o;
    }
}

// ---------- CSR build ----------
__global__ __launch_bounds__(256)
void hist_kernel(const int* __restrict__ dst, int* __restrict__ cnt, int E)
{
    int e = blockIdx.x * 256 + threadIdx.x;
    if (e < E) atomicAdd(&cnt[dst[e]], 1);
}

__global__ __launch_bounds__(256)
void scan1_kernel(const int* __restrict__ cnt, int* __restrict__ rowptr,
                  int* __restrict__ bsum, float* __restrict__ inv, int Nn)
{
    __shared__ int s[256];
    const int tid = threadIdx.x;
    const int g = blockIdx.x * 256 + tid;
    int v = (g < Nn) ? cnt[g] : 0;
    if (g < Nn) inv[g] = 1.0f / fmaxf((float)v, 1.0f);
    s[tid] = v;
    __syncthreads();
    for (int off = 1; off < 256; off <<= 1) {
        int t = (tid >= off) ? s[tid - off] : 0;
        __syncthreads();
        s[tid] += t;
        __syncthreads();
    }
    if (g < Nn) rowptr[g] = s[tid] - v;              // exclusive
    if (tid == 255) bsum[blockIdx.x] = s[255];
}

__global__ __launch_bounds__(256)
void scan2_kernel(int* __restrict__ bsum, int nb)
{
    __shared__ int s[256];
    const int tid = threadIdx.x;
    int v = (tid < nb) ? bsum[tid] : 0;
    s[tid] = v;
    __syncthreads();
    for (int off = 1; off < 256; off <<= 1) {
        int t = (tid >= off) ? s[tid - off] : 0;
        __syncthreads();
        s[tid] += t;
        __syncthreads();
    }
    if (tid < nb) bsum[tid] = s[tid] - v;            // exclusive
}

__global__ __launch_bounds__(256)
void scan3_kernel(int* __restrict__ rowptr, int* __restrict__ cursor,
                  const int* __restrict__ bsum, int Nn, int E)
{
    const int g = blockIdx.x * 256 + threadIdx.x;
    if (g < Nn) {
        int v = rowptr[g] + bsum[blockIdx.x];
        rowptr[g] = v;
        cursor[g] = v;
    }
    if (g == 0) rowptr[Nn] = E;
}

__global__ __launch_bounds__(256)
void fill_kernel(const int* __restrict__ src, const int* __restrict__ dst,
                 int* __restrict__ cursor, int* __restrict__ adj, int E)
{
    int e = blockIdx.x * 256 + threadIdx.x;
    if (e < E) {
        int pos = atomicAdd(&cursor[dst[e]], 1);
        adj[pos] = src[e];
    }
}

// ---------- gather-mean aggregation (bf16 in, bf16 out): one wave per node ----------
__global__ __launch_bounds__(256)
void gather_kernel(const ushort* __restrict__ xb, const int* __restrict__ rowptr,
                   const int* __restrict__ adj, const float* __restrict__ inv,
                   ushort* __restrict__ agg, int Nn)
{
    const int gwid = (blockIdx.x * 256 + threadIdx.x) >> 6;   // one wave per node
    const int lane = threadIdx.x & 63;
    if (gwid >= Nn) return;
    const int beg = rowptr[gwid];
    const int end = rowptr[gwid + 1];
    const int off = lane * 2;                                  // 2 bf16 per lane
    float ax = 0.f, ay = 0.f;
    int i = beg;
    for (; i + 1 < end; i += 2) {
        int s0 = adj[i], s1 = adj[i + 1];
        uint v0 = *reinterpret_cast<const uint*>(xb + (size_t)s0 * D + off);
        uint v1 = *reinterpret_cast<const uint*>(xb + (size_t)s1 * D + off);
        ax += __uint_as_float(v0 << 16) + __uint_as_float(v1 << 16);
        ay += __uint_as_float(v0 & 0xffff0000u) + __uint_as_float(v1 & 0xffff0000u);
    }
    if (i < end) {
        int s0 = adj[i];
        uint v0 = *reinterpret_cast<const uint*>(xb + (size_t)s0 * D + off);
        ax += __uint_as_float(v0 << 16);
        ay += __uint_as_float(v0 & 0xffff0000u);
    }
    const float sc = inv[gwid];
    uint p = f2bf(ax * sc) | (f2bf(ay * sc) << 16);
    *reinterpret_cast<uint*>(agg + (size_t)gwid * D + off) = p;
}

// ---------- MFMA GEMM + BN epilogue ----------
// out[n,j] = BN( sum_k aggb[n,k]*Wl[j,k] + selfb[n,k]*Wr[j,k] + b[j] ), opt ReLU.
// Block: 64 rows x 128 cols, 4 waves in 2x2 grid (wave: 32 rows x 64 cols).
// A(64x128) and W(128x128) staged bf16 in LDS, row-linear with ci^=(row&7) XOR
// swizzle (write and read) -> conflict-free ds_read_b128 fragments.
// mfma_f32_16x16x32_bf16: A/B frag: lane l holds row/col (l&15), k=(l>>4)*8+j;
// C/D: col=lane&15, row=(lane>>4)*4+reg  [m89-verified mapping].
__global__ __launch_bounds__(256)
void mfma_gemm_bn_kernel(const ushort* __restrict__ aggb,
                         const ushort* __restrict__ selfb,
                         const ushort* __restrict__ Wlb, const ushort* __restrict__ Wrb,
                         const float* __restrict__ bias,
                         const float* __restrict__ gamma, const float* __restrict__ beta,
                         const float* __restrict__ rmean, const float* __restrict__ rvar,
                         void* __restrict__ outp, int relu, int out_bf16, int Nn)
{
    __shared__ ushort Alds[BM * D];      // 16 KB
    __shared__ ushort Blds[D * D];       // 32 KB

    const int tid = threadIdx.x;
    const int lane = tid & 63;
    const int wid = tid >> 6;
    const int wr = wid >> 1;             // wave row-half (0/1): rows wr*32..+31
    const int wc = wid & 1;              // wave col-half (0/1): cols wc*64..+63
    const int nb = blockIdx.x * BM;

    const f32x4 z = {0.f, 0.f, 0.f, 0.f};
    f32x4 acc[2][4];
#pragma unroll
    for (int bi = 0; bi < 2; ++bi)
#pragma unroll
        for (int ti = 0; ti < 4; ++ti) acc[bi][ti] = z;

    for (int pass = 0; pass < 2; ++pass) {
        const ushort* __restrict__ A = pass ? selfb : aggb;
        const ushort* __restrict__ W = pass ? Wrb : Wlb;
        if (pass) __syncthreads();       // pass-0 reads done before restaging

        // stage A: 64 rows x 16 chunks(16B); swizzled LDS write (linear 1KB/wave)
#pragma unroll
        for (int it = 0; it < 4; ++it) {
            int c = it * 256 + tid;
            int row = c >> 4, ci = c & 15;
            int gn = nb + row;
            short8 v = {};
            if (gn < Nn) v = *reinterpret_cast<const short8*>(A + (size_t)gn * D + ci * 8);
            *reinterpret_cast<short8*>(&Alds[row * D + ((ci ^ (row & 7)) * 8)]) = v;
        }
        // stage W: 128 rows x 16 chunks
#pragma unroll
        for (int it = 0; it < 8; ++it) {
            int c = it * 256 + tid;
            int j = c >> 4, ci = c & 15;
            short8 w = *reinterpret_cast<const short8*>(W + j * D + ci * 8);
            *reinterpret_cast<short8*>(&Blds[j * D + ((ci ^ (j & 7)) * 8)]) = w;
        }
        __syncthreads();

#pragma unroll
        for (int ks = 0; ks < 4; ++ks) {             // K chunks of 32
            const int kg = lane >> 4;                // k-group 0..3
            const int ci = ks * 4 + kg;
            short8 af[2], bfr[4];
#pragma unroll
            for (int bi = 0; bi < 2; ++bi) {
                int row = wr * 32 + bi * 16 + (lane & 15);
                af[bi] = *reinterpret_cast<const short8*>(
                    &Alds[row * D + ((ci ^ (row & 7)) * 8)]);
            }
#pragma unroll
            for (int ti = 0; ti < 4; ++ti) {
                int j = wc * 64 + ti * 16 + (lane & 15);
                bfr[ti] = *reinterpret_cast<const short8*>(
                    &Blds[j * D + ((ci ^ (j & 7)) * 8)]);
            }
#pragma unroll
            for (int bi = 0; bi < 2; ++bi)
#pragma unroll
                for (int ti = 0; ti < 4; ++ti)
                    acc[bi][ti] = __builtin_amdgcn_mfma_f32_16x16x32_bf16(
                        af[bi], bfr[ti], acc[bi][ti], 0, 0, 0);
        }
    }

    // epilogue: bias + BN fused per-column scale/shift; optional ReLU
#pragma unroll
    for (int ti = 0; ti < 4; ++ti) {
        int col = wc * 64 + ti * 16 + (lane & 15);
        float sc = gamma[col] * rsqrtf(rvar[col] + 1e-5f);
        float sh = bias[col] * sc + beta[col] - rmean[col] * sc;
#pragma unroll
        for (int bi = 0; bi < 2; ++bi) {
#pragma unroll
            for (int r = 0; r < 4; ++r) {
                int row = nb + wr * 32 + bi * 16 + (lane >> 4) * 4 + r;
                if (row < Nn) {
                    float v = acc[bi][ti][r] * sc + sh;
                    if (relu) v = fmaxf(v, 0.f);
                    if (out_bf16)
                        ((ushort*)outp)[(size_t)row * D + col] = (ushort)f2bf(v);
                    else
                        ((float*)outp)[(size_t)row * D + col] = v;
                }
            }
        }
    }
}

extern "C" void kernel_launch(void* const* d_in, const int* in_sizes, int n_in,
                              void* d_out, int out_size, void* d_ws, size_t ws_size,
                              hipStream_t stream)
{
    const float* x   = (const float*)d_in[0];
    const int*   ei  = (const int*)d_in[1];
    const float* Wl0 = (const float*)d_in[2];
    const float* Wr0 = (const float*)d_in[3];
    const float* b0  = (const float*)d_in[4];
    const float* g0  = (const float*)d_in[5];
    const float* be0 = (const float*)d_in[6];
    const float* rm0 = (const float*)d_in[7];
    const float* rv0 = (const float*)d_in[8];
    const float* Wl1 = (const float*)d_in[9];
    const float* Wr1 = (const float*)d_in[10];
    const float* b1  = (const float*)d_in[11];
    const float* g1  = (const float*)d_in[12];
    const float* be1 = (const float*)d_in[13];
    const float* rm1 = (const float*)d_in[14];
    const float* rv1 = (const float*)d_in[15];

    const int N = in_sizes[0] / D;
    const int E = in_sizes[1] / 2;
    const int* src = ei;
    const int* dst = ei + E;

    // workspace: xb u16[N*D] | aggb u16[N*D] | h0b u16[N*D] | wbf u16[4*16384] |
    //            inv f[N] | cnt i[N] | rowptr i[N+1] | cursor i[N] | bsum i[256] | adj i[E]
    ushort* xb    = (ushort*)d_ws;
    ushort* aggb  = xb + (size_t)N * D;
    ushort* h0b   = aggb + (size_t)N * D;
    ushort* wbf   = h0b + (size_t)N * D;
    float*  inv   = (float*)(wbf + 4 * 16384);
    int*    cnt    = (int*)(inv + N);
    int*    rowptr = cnt + N;
    int*    cursor = rowptr + (N + 1);
    int*    bsum   = cursor + N;
    int*    adj    = bsum + 256;

    ushort* wl0b = wbf;
    ushort* wr0b = wbf + 16384;
    ushort* wl1b = wbf + 2 * 16384;
    ushort* wr1b = wbf + 3 * 16384;

    float* out = (float*)d_out;

    const int eblocks = (E + 255) / 256;
    const int nblocks = (N + 255) / 256;
    const int gemm_blocks = (N + BM - 1) / BM;
    const int gather_blocks = (N * 64 + 255) / 256;

    // ---- dtype conversion ----
    convert_f2b_kernel<<<(N * D / 4 + 255) / 256, 256, 0, stream>>>(x, xb, N * D / 4);
    convert_f2b_kernel<<<16, 256, 0, stream>>>(Wl0, wl0b, 4096);
    convert_f2b_kernel<<<16, 256, 0, stream>>>(Wr0, wr0b, 4096);
    convert_f2b_kernel<<<16, 256, 0, stream>>>(Wl1, wl1b, 4096);
    convert_f2b_kernel<<<16, 256, 0, stream>>>(Wr1, wr1b, 4096);

    // ---- CSR build (shared by both layers) ----
    hipMemsetAsync(cnt, 0, sizeof(int) * N, stream);
    hist_kernel<<<eblocks, 256, 0, stream>>>(dst, cnt, E);
    scan1_kernel<<<nblocks, 256, 0, stream>>>(cnt, rowptr, bsum, inv, N);
    scan2_kernel<<<1, 256, 0, stream>>>(bsum, nblocks);
    scan3_kernel<<<nblocks, 256, 0, stream>>>(rowptr, cursor, bsum, N, E);
    fill_kernel<<<eblocks, 256, 0, stream>>>(src, dst, cursor, adj, E);

    // ---- layer 0 ----
    gather_kernel<<<gather_blocks, 256, 0, stream>>>(xb, rowptr, adj, inv, aggb, N);
    mfma_gemm_bn_kernel<<<gemm_blocks, 256, 0, stream>>>(
        aggb, xb, wl0b, wr0b, b0, g0, be0, rm0, rv0, h0b, 1, 1, N);
    // ---- layer 1 ----
    gather_kernel<<<gather_blocks, 256, 0, stream>>>(h0b, rowptr, adj, inv, aggb, N);
    mfma_gemm_bn_kernel<<<gemm_blocks, 256, 0, stream>>>(
        aggb, h0b, wl1b, wr1b, b1, g1, be1, rm1, rv1, out, 0, 0, N);
}

// Round 10
// 304.863 us; speedup vs baseline: 11.0022x; 1.0941x over previous
//
#include <hip/hip_runtime.h>
#include <hip/hip_bf16.h>

// GraphSAGE 2-layer forward.
//   layer l: h = BN_l( mean_agg(h_in) @ Wl_l^T + h_in @ Wr_l^T + b_l ); ReLU after layer 0.
// Round 1: CSR-by-dst build + gather-mean aggregation (killed fp32 atomics; 3354 -> 804us).
// Round 3: register-tiled fp32 GEMM (804 -> 428us; gemm 266 -> 70us).
// Round 5: bf16 + mfma_f32_16x16x32_bf16 GEMM, XOR-swizzled LDS (428 -> 334us;
//          gather 52us x2 now dominant; gemm fell out of top-5; absmax 0.031).
// Round 8: gather unroll-4 (latency-bound: VALUBusy 27%, HBM 22%, occ 64% ->
//          need more loads in flight); fuse 5 convert kernels into 1 (-4 dispatches).
// Round 9: unchanged resubmit (round-8 bench hit GPUAcquisitionTimeout).

#define D 128
#define BM 64

typedef __attribute__((ext_vector_type(8))) short short8;   // 8 bf16 (4 VGPRs)
typedef __attribute__((ext_vector_type(4))) float f32x4;

__device__ inline uint f2bf(float f) {   // fp32 -> bf16 bits, round-to-nearest-even
    uint u = __float_as_uint(f);
    return (u + 0x7fffu + ((u >> 16) & 1u)) >> 16;
}

// ---------- dtype conversion: x + all 4 weight matrices in one kernel ----------
__global__ __launch_bounds__(256)
void convert_all_kernel(const float* __restrict__ x, ushort* __restrict__ xb, int n4x,
                        const float* __restrict__ w0, const float* __restrict__ w1,
                        const float* __restrict__ w2, const float* __restrict__ w3,
                        ushort* __restrict__ wb)
{
    int i = blockIdx.x * 256 + threadIdx.x;
    if (i < n4x) {
        float4 v = reinterpret_cast<const float4*>(x)[i];
        ushort4 o;
        o.x = (ushort)f2bf(v.x);
        o.y = (ushort)f2bf(v.y);
        o.z = (ushort)f2bf(v.z);
        o.w = (ushort)f2bf(v.w);
        reinterpret_cast<ushort4*>(xb)[i] = o;
    } else {
        int j = i - n4x;                 // 0..16383: 4 matrices x 4096 float4
        if (j < 16384) {
            const float* w = (j < 8192) ? ((j < 4096) ? w0 : w1)
                                        : ((j < 12288) ? w2 : w3);
            float4 v = reinterpret_cast<const float4*>(w)[j & 4095];
            ushort4 o;
            o.x = (ushort)f2bf(v.x);
            o.y = (ushort)f2bf(v.y);
            o.z = (ushort)f2bf(v.z);
            o.w = (ushort)f2bf(v.w);
            reinterpret_cast<ushort4*>(wb)[j] = o;   // wb = 4 contiguous 128x128 bf16
        }
    }
}

// ---------- CSR build ----------
__global__ __launch_bounds__(256)
void hist_kernel(const int* __restrict__ dst, int* __restrict__ cnt, int E)
{
    int e = blockIdx.x * 256 + threadIdx.x;
    if (e < E) atomicAdd(&cnt[dst[e]], 1);
}

__global__ __launch_bounds__(256)
void scan1_kernel(const int* __restrict__ cnt, int* __restrict__ rowptr,
                  int* __restrict__ bsum, float* __restrict__ inv, int Nn)
{
    __shared__ int s[256];
    const int tid = threadIdx.x;
    const int g = blockIdx.x * 256 + tid;
    int v = (g < Nn) ? cnt[g] : 0;
    if (g < Nn) inv[g] = 1.0f / fmaxf((float)v, 1.0f);
    s[tid] = v;
    __syncthreads();
    for (int off = 1; off < 256; off <<= 1) {
        int t = (tid >= off) ? s[tid - off] : 0;
        __syncthreads();
        s[tid] += t;
        __syncthreads();
    }
    if (g < Nn) rowptr[g] = s[tid] - v;              // exclusive
    if (tid == 255) bsum[blockIdx.x] = s[255];
}

__global__ __launch_bounds__(256)
void scan2_kernel(int* __restrict__ bsum, int nb)
{
    __shared__ int s[256];
    const int tid = threadIdx.x;
    int v = (tid < nb) ? bsum[tid] : 0;
    s[tid] = v;
    __syncthreads();
    for (int off = 1; off < 256; off <<= 1) {
        int t = (tid >= off) ? s[tid - off] : 0;
        __syncthreads();
        s[tid] += t;
        __syncthreads();
    }
    if (tid < nb) bsum[tid] = s[tid] - v;            // exclusive
}

__global__ __launch_bounds__(256)
void scan3_kernel(int* __restrict__ rowptr, int* __restrict__ cursor,
                  const int* __restrict__ bsum, int Nn, int E)
{
    const int g = blockIdx.x * 256 + threadIdx.x;
    if (g < Nn) {
        int v = rowptr[g] + bsum[blockIdx.x];
        rowptr[g] = v;
        cursor[g] = v;
    }
    if (g == 0) rowptr[Nn] = E;
}

__global__ __launch_bounds__(256)
void fill_kernel(const int* __restrict__ src, const int* __restrict__ dst,
                 int* __restrict__ cursor, int* __restrict__ adj, int E)
{
    int e = blockIdx.x * 256 + threadIdx.x;
    if (e < E) {
        int pos = atomicAdd(&cursor[dst[e]], 1);
        adj[pos] = src[e];
    }
}

// ---------- gather-mean aggregation (bf16 in, bf16 out): one wave per node ----------
// unroll-4: 4 independent neighbor-row loads in flight (latency-bound fix)
__global__ __launch_bounds__(256)
void gather_kernel(const ushort* __restrict__ xb, const int* __restrict__ rowptr,
                   const int* __restrict__ adj, const float* __restrict__ inv,
                   ushort* __restrict__ agg, int Nn)
{
    const int gwid = (blockIdx.x * 256 + threadIdx.x) >> 6;   // one wave per node
    const int lane = threadIdx.x & 63;
    if (gwid >= Nn) return;
    const int beg = rowptr[gwid];
    const int end = rowptr[gwid + 1];
    const int off = lane * 2;                                  // 2 bf16 per lane
    float ax = 0.f, ay = 0.f;
    int i = beg;
    for (; i + 3 < end; i += 4) {
        int s0 = adj[i], s1 = adj[i + 1], s2 = adj[i + 2], s3 = adj[i + 3];
        uint v0 = *reinterpret_cast<const uint*>(xb + (size_t)s0 * D + off);
        uint v1 = *reinterpret_cast<const uint*>(xb + (size_t)s1 * D + off);
        uint v2 = *reinterpret_cast<const uint*>(xb + (size_t)s2 * D + off);
        uint v3 = *reinterpret_cast<const uint*>(xb + (size_t)s3 * D + off);
        ax += __uint_as_float(v0 << 16) + __uint_as_float(v1 << 16)
            + __uint_as_float(v2 << 16) + __uint_as_float(v3 << 16);
        ay += __uint_as_float(v0 & 0xffff0000u) + __uint_as_float(v1 & 0xffff0000u)
            + __uint_as_float(v2 & 0xffff0000u) + __uint_as_float(v3 & 0xffff0000u);
    }
    for (; i < end; ++i) {
        uint v0 = *reinterpret_cast<const uint*>(xb + (size_t)adj[i] * D + off);
        ax += __uint_as_float(v0 << 16);
        ay += __uint_as_float(v0 & 0xffff0000u);
    }
    const float sc = inv[gwid];
    uint p = f2bf(ax * sc) | (f2bf(ay * sc) << 16);
    *reinterpret_cast<uint*>(agg + (size_t)gwid * D + off) = p;
}

// ---------- MFMA GEMM + BN epilogue ----------
// out[n,j] = BN( sum_k aggb[n,k]*Wl[j,k] + selfb[n,k]*Wr[j,k] + b[j] ), opt ReLU.
// Block: 64 rows x 128 cols, 4 waves in 2x2 grid (wave: 32 rows x 64 cols).
// A(64x128) and W(128x128) staged bf16 in LDS, row-linear with ci^=(row&7) XOR
// swizzle (write and read) -> conflict-free ds_read_b128 fragments.
// mfma_f32_16x16x32_bf16: A/B frag: lane l holds row/col (l&15), k=(l>>4)*8+j;
// C/D: col=lane&15, row=(lane>>4)*4+reg  [m89-verified mapping].
__global__ __launch_bounds__(256)
void mfma_gemm_bn_kernel(const ushort* __restrict__ aggb,
                         const ushort* __restrict__ selfb,
                         const ushort* __restrict__ Wlb, const ushort* __restrict__ Wrb,
                         const float* __restrict__ bias,
                         const float* __restrict__ gamma, const float* __restrict__ beta,
                         const float* __restrict__ rmean, const float* __restrict__ rvar,
                         void* __restrict__ outp, int relu, int out_bf16, int Nn)
{
    __shared__ ushort Alds[BM * D];      // 16 KB
    __shared__ ushort Blds[D * D];       // 32 KB

    const int tid = threadIdx.x;
    const int lane = tid & 63;
    const int wid = tid >> 6;
    const int wr = wid >> 1;             // wave row-half (0/1): rows wr*32..+31
    const int wc = wid & 1;              // wave col-half (0/1): cols wc*64..+63
    const int nb = blockIdx.x * BM;

    const f32x4 z = {0.f, 0.f, 0.f, 0.f};
    f32x4 acc[2][4];
#pragma unroll
    for (int bi = 0; bi < 2; ++bi)
#pragma unroll
        for (int ti = 0; ti < 4; ++ti) acc[bi][ti] = z;

    for (int pass = 0; pass < 2; ++pass) {
        const ushort* __restrict__ A = pass ? selfb : aggb;
        const ushort* __restrict__ W = pass ? Wrb : Wlb;
        if (pass) __syncthreads();       // pass-0 reads done before restaging

        // stage A: 64 rows x 16 chunks(16B); swizzled LDS write
#pragma unroll
        for (int it = 0; it < 4; ++it) {
            int c = it * 256 + tid;
            int row = c >> 4, ci = c & 15;
            int gn = nb + row;
            short8 v = {};
            if (gn < Nn) v = *reinterpret_cast<const short8*>(A + (size_t)gn * D + ci * 8);
            *reinterpret_cast<short8*>(&Alds[row * D + ((ci ^ (row & 7)) * 8)]) = v;
        }
        // stage W: 128 rows x 16 chunks
#pragma unroll
        for (int it = 0; it < 8; ++it) {
            int c = it * 256 + tid;
            int j = c >> 4, ci = c & 15;
            short8 w = *reinterpret_cast<const short8*>(W + j * D + ci * 8);
            *reinterpret_cast<short8*>(&Blds[j * D + ((ci ^ (j & 7)) * 8)]) = w;
        }
        __syncthreads();

#pragma unroll
        for (int ks = 0; ks < 4; ++ks) {             // K chunks of 32
            const int kg = lane >> 4;                // k-group 0..3
            const int ci = ks * 4 + kg;
            short8 af[2], bfr[4];
#pragma unroll
            for (int bi = 0; bi < 2; ++bi) {
                int row = wr * 32 + bi * 16 + (lane & 15);
                af[bi] = *reinterpret_cast<const short8*>(
                    &Alds[row * D + ((ci ^ (row & 7)) * 8)]);
            }
#pragma unroll
            for (int ti = 0; ti < 4; ++ti) {
                int j = wc * 64 + ti * 16 + (lane & 15);
                bfr[ti] = *reinterpret_cast<const short8*>(
                    &Blds[j * D + ((ci ^ (j & 7)) * 8)]);
            }
#pragma unroll
            for (int bi = 0; bi < 2; ++bi)
#pragma unroll
                for (int ti = 0; ti < 4; ++ti)
                    acc[bi][ti] = __builtin_amdgcn_mfma_f32_16x16x32_bf16(
                        af[bi], bfr[ti], acc[bi][ti], 0, 0, 0);
        }
    }

    // epilogue: bias + BN fused per-column scale/shift; optional ReLU
#pragma unroll
    for (int ti = 0; ti < 4; ++ti) {
        int col = wc * 64 + ti * 16 + (lane & 15);
        float sc = gamma[col] * rsqrtf(rvar[col] + 1e-5f);
        float sh = bias[col] * sc + beta[col] - rmean[col] * sc;
#pragma unroll
        for (int bi = 0; bi < 2; ++bi) {
#pragma unroll
            for (int r = 0; r < 4; ++r) {
                int row = nb + wr * 32 + bi * 16 + (lane >> 4) * 4 + r;
                if (row < Nn) {
                    float v = acc[bi][ti][r] * sc + sh;
                    if (relu) v = fmaxf(v, 0.f);
                    if (out_bf16)
                        ((ushort*)outp)[(size_t)row * D + col] = (ushort)f2bf(v);
                    else
                        ((float*)outp)[(size_t)row * D + col] = v;
                }
            }
        }
    }
}

extern "C" void kernel_launch(void* const* d_in, const int* in_sizes, int n_in,
                              void* d_out, int out_size, void* d_ws, size_t ws_size,
                              hipStream_t stream)
{
    const float* x   = (const float*)d_in[0];
    const int*   ei  = (const int*)d_in[1];
    const float* Wl0 = (const float*)d_in[2];
    const float* Wr0 = (const float*)d_in[3];
    const float* b0  = (const float*)d_in[4];
    const float* g0  = (const float*)d_in[5];
    const float* be0 = (const float*)d_in[6];
    const float* rm0 = (const float*)d_in[7];
    const float* rv0 = (const float*)d_in[8];
    const float* Wl1 = (const float*)d_in[9];
    const float* Wr1 = (const float*)d_in[10];
    const float* b1  = (const float*)d_in[11];
    const float* g1  = (const float*)d_in[12];
    const float* be1 = (const float*)d_in[13];
    const float* rm1 = (const float*)d_in[14];
    const float* rv1 = (const float*)d_in[15];

    const int N = in_sizes[0] / D;
    const int E = in_sizes[1] / 2;
    const int* src = ei;
    const int* dst = ei + E;

    // workspace: xb u16[N*D] | aggb u16[N*D] | h0b u16[N*D] | wbf u16[4*16384] |
    //            inv f[N] | cnt i[N] | rowptr i[N+1] | cursor i[N] | bsum i[256] | adj i[E]
    ushort* xb    = (ushort*)d_ws;
    ushort* aggb  = xb + (size_t)N * D;
    ushort* h0b   = aggb + (size_t)N * D;
    ushort* wbf   = h0b + (size_t)N * D;
    float*  inv   = (float*)(wbf + 4 * 16384);
    int*    cnt    = (int*)(inv + N);
    int*    rowptr = cnt + N;
    int*    cursor = rowptr + (N + 1);
    int*    bsum   = cursor + N;
    int*    adj    = bsum + 256;

    ushort* wl0b = wbf;
    ushort* wr0b = wbf + 16384;
    ushort* wl1b = wbf + 2 * 16384;
    ushort* wr1b = wbf + 3 * 16384;

    float* out = (float*)d_out;

    const int eblocks = (E + 255) / 256;
    const int nblocks = (N + 255) / 256;
    const int gemm_blocks = (N + BM - 1) / BM;
    const int gather_blocks = (N * 64 + 255) / 256;

    // ---- dtype conversion (x + all 4 weights, one kernel) ----
    const int n4x = N * D / 4;
    convert_all_kernel<<<(n4x + 16384 + 255) / 256, 256, 0, stream>>>(
        x, xb, n4x, Wl0, Wr0, Wl1, Wr1, wbf);

    // ---- CSR build (shared by both layers) ----
    hipMemsetAsync(cnt, 0, sizeof(int) * N, stream);
    hist_kernel<<<eblocks, 256, 0, stream>>>(dst, cnt, E);
    scan1_kernel<<<nblocks, 256, 0, stream>>>(cnt, rowptr, bsum, inv, N);
    scan2_kernel<<<1, 256, 0, stream>>>(bsum, nblocks);
    scan3_kernel<<<nblocks, 256, 0, stream>>>(rowptr, cursor, bsum, N, E);
    fill_kernel<<<eblocks, 256, 0, stream>>>(src, dst, cursor, adj, E);

    // ---- layer 0 ----
    gather_kernel<<<gather_blocks, 256, 0, stream>>>(xb, rowptr, adj, inv, aggb, N);
    mfma_gemm_bn_kernel<<<gemm_blocks, 256, 0, stream>>>(
        aggb, xb, wl0b, wr0b, b0, g0, be0, rm0, rv0, h0b, 1, 1, N);
    // ---- layer 1 ----
    gather_kernel<<<gather_blocks, 256, 0, stream>>>(h0b, rowptr, adj, inv, aggb, N);
    mfma_gemm_bn_kernel<<<gemm_blocks, 256, 0, stream>>>(
        aggb, h0b, wl1b, wr1b, b1, g1, be1, rm1, rv1, out, 0, 0, N);
}

// Round 11
// 275.457 us; speedup vs baseline: 12.1767x; 1.1068x over previous
//
#include <hip/hip_runtime.h>
#include <hip/hip_bf16.h>

// GraphSAGE 2-layer forward.
//   layer l: h = BN_l( mean_agg(h_in) @ Wl_l^T + h_in @ Wr_l^T + b_l ); ReLU after layer 0.
// Round 1:  CSR gather-mean (killed fp32 atomics; 3354 -> 804us).
// Round 3:  register-tiled fp32 GEMM (804 -> 428us).
// Round 5:  bf16 + mfma_f32_16x16x32_bf16 GEMM, XOR-swizzled LDS (428 -> 334us).
// Round 8:  gather unroll-4 + fused converts (334 -> 305us).
// Round 10: fill_kernel = 52us random-scatter-write bound (WRITE_SIZE 52MB = 800K x 64B
//           line writebacks; VALU 0.4%). Random READS replicate across XCD L2s but
//           random WRITES ping-pong -> replace CSR (memset+hist+3 scans+fill, ~100us,
//           6 dispatches) with linked-list adjacency:
//           build: atomicExch(&head[dst],e); next[e]=old  (1 atomic + coalesced write)
//           gather: walk list, 4 nodes/wave, degree counted inline (chase latency
//           ~10us hidden under BW-bound row loads). 11 dispatches -> 6.

#define D 128
#define BM 64

typedef __attribute__((ext_vector_type(8))) short short8;   // 8 bf16 (4 VGPRs)
typedef __attribute__((ext_vector_type(4))) float f32x4;

__device__ inline uint f2bf(float f) {   // fp32 -> bf16 bits, round-to-nearest-even
    uint u = __float_as_uint(f);
    return (u + 0x7fffu + ((u >> 16) & 1u)) >> 16;
}

// ---------- fused: dtype conversion (x + 4 weights) || linked-list build ----------
// blocks [0, CB): convert; blocks [CB, CB+EB): list build. Independent work.
__global__ __launch_bounds__(256)
void convert_build_kernel(const float* __restrict__ x, ushort* __restrict__ xb, int n4x,
                          const float* __restrict__ w0, const float* __restrict__ w1,
                          const float* __restrict__ w2, const float* __restrict__ w3,
                          ushort* __restrict__ wb, int CB,
                          const int* __restrict__ dst, int* __restrict__ head,
                          int* __restrict__ nxt, int E)
{
    if ((int)blockIdx.x < CB) {
        int i = blockIdx.x * 256 + threadIdx.x;
        if (i < n4x) {
            float4 v = reinterpret_cast<const float4*>(x)[i];
            ushort4 o;
            o.x = (ushort)f2bf(v.x);
            o.y = (ushort)f2bf(v.y);
            o.z = (ushort)f2bf(v.z);
            o.w = (ushort)f2bf(v.w);
            reinterpret_cast<ushort4*>(xb)[i] = o;
        } else {
            int j = i - n4x;                 // 0..16383: 4 matrices x 4096 float4
            if (j < 16384) {
                const float* w = (j < 8192) ? ((j < 4096) ? w0 : w1)
                                            : ((j < 12288) ? w2 : w3);
                float4 v = reinterpret_cast<const float4*>(w)[j & 4095];
                ushort4 o;
                o.x = (ushort)f2bf(v.x);
                o.y = (ushort)f2bf(v.y);
                o.z = (ushort)f2bf(v.z);
                o.w = (ushort)f2bf(v.w);
                reinterpret_cast<ushort4*>(wb)[j] = o;   // 4 contiguous 128x128 bf16
            }
        }
    } else {
        int e = (blockIdx.x - CB) * 256 + threadIdx.x;
        if (e < E) {
            int d = dst[e];
            int old = atomicExch(&head[d], e);   // random atomic (like hist)
            nxt[e] = old;                         // coalesced write
        }
    }
}

// ---------- gather-mean via list walk: 4 nodes per wave, 16 lanes/node ----------
// Per hop: nxt[e] is the only serial dependence; srcArr[e] + row load pipeline
// behind it. 4 independent chains per wave; ~all waves co-resident -> chase
// latency hidden under BW-bound short8 row loads. Degree counted inline.
__global__ __launch_bounds__(256)
void gather_list_kernel(const ushort* __restrict__ xb, const int* __restrict__ head,
                        const int* __restrict__ nxt, const int* __restrict__ srcArr,
                        ushort* __restrict__ agg, int Nn)
{
    const int gtid = blockIdx.x * 256 + threadIdx.x;
    const int wave = gtid >> 6;
    const int lane = threadIdx.x & 63;
    const int grp  = lane >> 4;          // 0..3 : node within wave
    const int gl   = lane & 15;          // lane within group: 8 bf16 columns
    const int node = wave * 4 + grp;
    if (node >= Nn) return;              // Nn % 4 == 0 -> wave-uniform

    float acc[8] = {0.f, 0.f, 0.f, 0.f, 0.f, 0.f, 0.f, 0.f};
    int cnt = 0;
    int e = head[node];                  // uniform within group -> broadcast load
    while (__any(e >= 0)) {
        if (e >= 0) {
            int s = srcArr[e];
            short8 v = *reinterpret_cast<const short8*>(xb + (size_t)s * D + gl * 8);
#pragma unroll
            for (int j = 0; j < 8; ++j)
                acc[j] += __uint_as_float(((uint)(ushort)v[j]) << 16);
            ++cnt;
            e = nxt[e];
        }
    }
    const float sc = 1.0f / fmaxf((float)cnt, 1.0f);
    uint o[4];
#pragma unroll
    for (int j = 0; j < 4; ++j)
        o[j] = f2bf(acc[2 * j] * sc) | (f2bf(acc[2 * j + 1] * sc) << 16);
    *reinterpret_cast<uint4*>(agg + (size_t)node * D + gl * 8) =
        make_uint4(o[0], o[1], o[2], o[3]);
}

// ---------- MFMA GEMM + BN epilogue (unchanged from verified round 5) ----------
// out[n,j] = BN( sum_k aggb[n,k]*Wl[j,k] + selfb[n,k]*Wr[j,k] + b[j] ), opt ReLU.
// Block: 64 rows x 128 cols, 4 waves in 2x2 grid (wave: 32 rows x 64 cols).
// A(64x128) and W(128x128) staged bf16 in LDS, row-linear with ci^=(row&7) XOR
// swizzle (write and read) -> conflict-free ds_read_b128 fragments.
// mfma_f32_16x16x32_bf16: A/B frag: lane l holds row/col (l&15), k=(l>>4)*8+j;
// C/D: col=lane&15, row=(lane>>4)*4+reg  [m89-verified mapping].
__global__ __launch_bounds__(256)
void mfma_gemm_bn_kernel(const ushort* __restrict__ aggb,
                         const ushort* __restrict__ selfb,
                         const ushort* __restrict__ Wlb, const ushort* __restrict__ Wrb,
                         const float* __restrict__ bias,
                         const float* __restrict__ gamma, const float* __restrict__ beta,
                         const float* __restrict__ rmean, const float* __restrict__ rvar,
                         void* __restrict__ outp, int relu, int out_bf16, int Nn)
{
    __shared__ ushort Alds[BM * D];      // 16 KB
    __shared__ ushort Blds[D * D];       // 32 KB

    const int tid = threadIdx.x;
    const int lane = tid & 63;
    const int wid = tid >> 6;
    const int wr = wid >> 1;             // wave row-half (0/1): rows wr*32..+31
    const int wc = wid & 1;              // wave col-half (0/1): cols wc*64..+63
    const int nb = blockIdx.x * BM;

    const f32x4 z = {0.f, 0.f, 0.f, 0.f};
    f32x4 acc[2][4];
#pragma unroll
    for (int bi = 0; bi < 2; ++bi)
#pragma unroll
        for (int ti = 0; ti < 4; ++ti) acc[bi][ti] = z;

    for (int pass = 0; pass < 2; ++pass) {
        const ushort* __restrict__ A = pass ? selfb : aggb;
        const ushort* __restrict__ W = pass ? Wrb : Wlb;
        if (pass) __syncthreads();       // pass-0 reads done before restaging

        // stage A: 64 rows x 16 chunks(16B); swizzled LDS write
#pragma unroll
        for (int it = 0; it < 4; ++it) {
            int c = it * 256 + tid;
            int row = c >> 4, ci = c & 15;
            int gn = nb + row;
            short8 v = {};
            if (gn < Nn) v = *reinterpret_cast<const short8*>(A + (size_t)gn * D + ci * 8);
            *reinterpret_cast<short8*>(&Alds[row * D + ((ci ^ (row & 7)) * 8)]) = v;
        }
        // stage W: 128 rows x 16 chunks
#pragma unroll
        for (int it = 0; it < 8; ++it) {
            int c = it * 256 + tid;
            int j = c >> 4, ci = c & 15;
            short8 w = *reinterpret_cast<const short8*>(W + j * D + ci * 8);
            *reinterpret_cast<short8*>(&Blds[j * D + ((ci ^ (j & 7)) * 8)]) = w;
        }
        __syncthreads();

#pragma unroll
        for (int ks = 0; ks < 4; ++ks) {             // K chunks of 32
            const int kg = lane >> 4;                // k-group 0..3
            const int ci = ks * 4 + kg;
            short8 af[2], bfr[4];
#pragma unroll
            for (int bi = 0; bi < 2; ++bi) {
                int row = wr * 32 + bi * 16 + (lane & 15);
                af[bi] = *reinterpret_cast<const short8*>(
                    &Alds[row * D + ((ci ^ (row & 7)) * 8)]);
            }
#pragma unroll
            for (int ti = 0; ti < 4; ++ti) {
                int j = wc * 64 + ti * 16 + (lane & 15);
                bfr[ti] = *reinterpret_cast<const short8*>(
                    &Blds[j * D + ((ci ^ (j & 7)) * 8)]);
            }
#pragma unroll
            for (int bi = 0; bi < 2; ++bi)
#pragma unroll
                for (int ti = 0; ti < 4; ++ti)
                    acc[bi][ti] = __builtin_amdgcn_mfma_f32_16x16x32_bf16(
                        af[bi], bfr[ti], acc[bi][ti], 0, 0, 0);
        }
    }

    // epilogue: bias + BN fused per-column scale/shift; optional ReLU
#pragma unroll
    for (int ti = 0; ti < 4; ++ti) {
        int col = wc * 64 + ti * 16 + (lane & 15);
        float sc = gamma[col] * rsqrtf(rvar[col] + 1e-5f);
        float sh = bias[col] * sc + beta[col] - rmean[col] * sc;
#pragma unroll
        for (int bi = 0; bi < 2; ++bi) {
#pragma unroll
            for (int r = 0; r < 4; ++r) {
                int row = nb + wr * 32 + bi * 16 + (lane >> 4) * 4 + r;
                if (row < Nn) {
                    float v = acc[bi][ti][r] * sc + sh;
                    if (relu) v = fmaxf(v, 0.f);
                    if (out_bf16)
                        ((ushort*)outp)[(size_t)row * D + col] = (ushort)f2bf(v);
                    else
                        ((float*)outp)[(size_t)row * D + col] = v;
                }
            }
        }
    }
}

extern "C" void kernel_launch(void* const* d_in, const int* in_sizes, int n_in,
                              void* d_out, int out_size, void* d_ws, size_t ws_size,
                              hipStream_t stream)
{
    const float* x   = (const float*)d_in[0];
    const int*   ei  = (const int*)d_in[1];
    const float* Wl0 = (const float*)d_in[2];
    const float* Wr0 = (const float*)d_in[3];
    const float* b0  = (const float*)d_in[4];
    const float* g0  = (const float*)d_in[5];
    const float* be0 = (const float*)d_in[6];
    const float* rm0 = (const float*)d_in[7];
    const float* rv0 = (const float*)d_in[8];
    const float* Wl1 = (const float*)d_in[9];
    const float* Wr1 = (const float*)d_in[10];
    const float* b1  = (const float*)d_in[11];
    const float* g1  = (const float*)d_in[12];
    const float* be1 = (const float*)d_in[13];
    const float* rm1 = (const float*)d_in[14];
    const float* rv1 = (const float*)d_in[15];

    const int N = in_sizes[0] / D;
    const int E = in_sizes[1] / 2;
    const int* src = ei;
    const int* dst = ei + E;

    // workspace: xb u16[N*D] | aggb u16[N*D] | h0b u16[N*D] | wbf u16[4*16384] |
    //            head i[N] | next i[E]
    ushort* xb   = (ushort*)d_ws;
    ushort* aggb = xb + (size_t)N * D;
    ushort* h0b  = aggb + (size_t)N * D;
    ushort* wbf  = h0b + (size_t)N * D;
    int*    head = (int*)(wbf + 4 * 16384);
    int*    nxt  = head + N;

    ushort* wl0b = wbf;
    ushort* wr0b = wbf + 16384;
    ushort* wl1b = wbf + 2 * 16384;
    ushort* wr1b = wbf + 3 * 16384;

    float* out = (float*)d_out;

    const int n4x = N * D / 4;
    const int CB  = (n4x + 16384 + 255) / 256;       // convert blocks
    const int EB  = (E + 255) / 256;                 // build blocks
    const int gemm_blocks = (N + BM - 1) / BM;
    const int gather_blocks = ((N + 3) / 4 * 64 + 255) / 256;   // 4 nodes per wave

    // ---- head = -1; then [convert || list-build] in one kernel ----
    hipMemsetAsync(head, 0xFF, sizeof(int) * N, stream);
    convert_build_kernel<<<CB + EB, 256, 0, stream>>>(
        x, xb, n4x, Wl0, Wr0, Wl1, Wr1, wbf, CB, dst, head, nxt, E);

    // ---- layer 0 ----
    gather_list_kernel<<<gather_blocks, 256, 0, stream>>>(xb, head, nxt, src, aggb, N);
    mfma_gemm_bn_kernel<<<gemm_blocks, 256, 0, stream>>>(
        aggb, xb, wl0b, wr0b, b0, g0, be0, rm0, rv0, h0b, 1, 1, N);
    // ---- layer 1 ----
    gather_list_kernel<<<gather_blocks, 256, 0, stream>>>(h0b, head, nxt, src, aggb, N);
    mfma_gemm_bn_kernel<<<gemm_blocks, 256, 0, stream>>>(
        aggb, h0b, wl1b, wr1b, b1, g1, be1, rm1, rv1, out, 0, 0, N);
}

// Round 17
// 274.209 us; speedup vs baseline: 12.2321x; 1.0046x over previous
//
#include <hip/hip_runtime.h>
#include <hip/hip_bf16.h>

// GraphSAGE 2-layer forward.
//   layer l: h = BN_l( mean_agg(h_in) @ Wl_l^T + h_in @ Wr_l^T + b_l ); ReLU after layer 0.
// Round 1:  CSR gather-mean (killed fp32 atomics; 3354 -> 804us).
// Round 3:  register-tiled fp32 GEMM (804 -> 428us).
// Round 5:  bf16 + mfma_f32_16x16x32_bf16 GEMM, XOR-swizzled LDS (428 -> 334us).
// Round 8:  gather unroll-4 + fused converts (334 -> 305us).
// Round 10: linked-list adjacency replaces CSR build (305 -> 275us; 11 -> 6 dispatches).
// Round 11: gather FETCH 139MB: TWO random 4B reads per hop (nxt[e], src[e]) = two
//           64B lines = ~102MB index traffic. Pack (src,next) into one int2 ->
//           one 8B random read per hop, halves index line fetches.
// Rounds 12-16: unchanged resubmits (GPUAcquisitionTimeout five rounds running).

#define D 128
#define BM 64

typedef __attribute__((ext_vector_type(8))) short short8;   // 8 bf16 (4 VGPRs)
typedef __attribute__((ext_vector_type(4))) float f32x4;

__device__ inline uint f2bf(float f) {   // fp32 -> bf16 bits, round-to-nearest-even
    uint u = __float_as_uint(f);
    return (u + 0x7fffu + ((u >> 16) & 1u)) >> 16;
}

// ---------- fused: dtype conversion (x + 4 weights) || linked-list build ----------
// blocks [0, CB): convert; blocks [CB, CB+EB): list build. Independent work.
__global__ __launch_bounds__(256)
void convert_build_kernel(const float* __restrict__ x, ushort* __restrict__ xb, int n4x,
                          const float* __restrict__ w0, const float* __restrict__ w1,
                          const float* __restrict__ w2, const float* __restrict__ w3,
                          ushort* __restrict__ wb, int CB,
                          const int* __restrict__ srcArr, const int* __restrict__ dst,
                          int* __restrict__ head, int2* __restrict__ nxt_src, int E)
{
    if ((int)blockIdx.x < CB) {
        int i = blockIdx.x * 256 + threadIdx.x;
        if (i < n4x) {
            float4 v = reinterpret_cast<const float4*>(x)[i];
            ushort4 o;
            o.x = (ushort)f2bf(v.x);
            o.y = (ushort)f2bf(v.y);
            o.z = (ushort)f2bf(v.z);
            o.w = (ushort)f2bf(v.w);
            reinterpret_cast<ushort4*>(xb)[i] = o;
        } else {
            int j = i - n4x;                 // 0..16383: 4 matrices x 4096 float4
            if (j < 16384) {
                const float* w = (j < 8192) ? ((j < 4096) ? w0 : w1)
                                            : ((j < 12288) ? w2 : w3);
                float4 v = reinterpret_cast<const float4*>(w)[j & 4095];
                ushort4 o;
                o.x = (ushort)f2bf(v.x);
                o.y = (ushort)f2bf(v.y);
                o.z = (ushort)f2bf(v.z);
                o.w = (ushort)f2bf(v.w);
                reinterpret_cast<ushort4*>(wb)[j] = o;   // 4 contiguous 128x128 bf16
            }
        }
    } else {
        int e = (blockIdx.x - CB) * 256 + threadIdx.x;
        if (e < E) {
            int s = srcArr[e];                    // coalesced
            int d = dst[e];                       // coalesced
            int old = atomicExch(&head[d], e);    // random atomic
            nxt_src[e] = make_int2(s, old);       // coalesced 8B write
        }
    }
}

// ---------- gather-mean via list walk: 4 nodes per wave, 16 lanes/node ----------
// Per hop: ONE random 8B read (src, next) packed; row load pipelines behind it.
// 4 independent chains per wave; ~all waves co-resident -> chase latency hidden
// under BW-bound short8 row loads. Degree counted inline.
__global__ __launch_bounds__(256)
void gather_list_kernel(const ushort* __restrict__ xb, const int* __restrict__ head,
                        const int2* __restrict__ nxt_src,
                        ushort* __restrict__ agg, int Nn)
{
    const int gtid = blockIdx.x * 256 + threadIdx.x;
    const int wave = gtid >> 6;
    const int lane = threadIdx.x & 63;
    const int grp  = lane >> 4;          // 0..3 : node within wave
    const int gl   = lane & 15;          // lane within group: 8 bf16 columns
    const int node = wave * 4 + grp;
    if (node >= Nn) return;

    float acc[8] = {0.f, 0.f, 0.f, 0.f, 0.f, 0.f, 0.f, 0.f};
    int cnt = 0;
    int e = head[node];                  // uniform within group -> broadcast load
    while (__any(e >= 0)) {
        if (e >= 0) {
            int2 p = nxt_src[e];         // one 8B random read: {src, next}
            short8 v = *reinterpret_cast<const short8*>(xb + (size_t)p.x * D + gl * 8);
#pragma unroll
            for (int j = 0; j < 8; ++j)
                acc[j] += __uint_as_float(((uint)(ushort)v[j]) << 16);
            ++cnt;
            e = p.y;
        }
    }
    const float sc = 1.0f / fmaxf((float)cnt, 1.0f);
    uint o[4];
#pragma unroll
    for (int j = 0; j < 4; ++j)
        o[j] = f2bf(acc[2 * j] * sc) | (f2bf(acc[2 * j + 1] * sc) << 16);
    *reinterpret_cast<uint4*>(agg + (size_t)node * D + gl * 8) =
        make_uint4(o[0], o[1], o[2], o[3]);
}

// ---------- MFMA GEMM + BN epilogue (unchanged from verified round 5) ----------
// out[n,j] = BN( sum_k aggb[n,k]*Wl[j,k] + selfb[n,k]*Wr[j,k] + b[j] ), opt ReLU.
// Block: 64 rows x 128 cols, 4 waves in 2x2 grid (wave: 32 rows x 64 cols).
// A(64x128) and W(128x128) staged bf16 in LDS, row-linear with ci^=(row&7) XOR
// swizzle (write and read) -> conflict-free ds_read_b128 fragments.
// mfma_f32_16x16x32_bf16: A/B frag: lane l holds row/col (l&15), k=(l>>4)*8+j;
// C/D: col=lane&15, row=(lane>>4)*4+reg  [m89-verified mapping].
__global__ __launch_bounds__(256)
void mfma_gemm_bn_kernel(const ushort* __restrict__ aggb,
                         const ushort* __restrict__ selfb,
                         const ushort* __restrict__ Wlb, const ushort* __restrict__ Wrb,
                         const float* __restrict__ bias,
                         const float* __restrict__ gamma, const float* __restrict__ beta,
                         const float* __restrict__ rmean, const float* __restrict__ rvar,
                         void* __restrict__ outp, int relu, int out_bf16, int Nn)
{
    __shared__ ushort Alds[BM * D];      // 16 KB
    __shared__ ushort Blds[D * D];       // 32 KB

    const int tid = threadIdx.x;
    const int lane = tid & 63;
    const int wid = tid >> 6;
    const int wr = wid >> 1;             // wave row-half (0/1): rows wr*32..+31
    const int wc = wid & 1;              // wave col-half (0/1): cols wc*64..+63
    const int nb = blockIdx.x * BM;

    const f32x4 z = {0.f, 0.f, 0.f, 0.f};
    f32x4 acc[2][4];
#pragma unroll
    for (int bi = 0; bi < 2; ++bi)
#pragma unroll
        for (int ti = 0; ti < 4; ++ti) acc[bi][ti] = z;

    for (int pass = 0; pass < 2; ++pass) {
        const ushort* __restrict__ A = pass ? selfb : aggb;
        const ushort* __restrict__ W = pass ? Wrb : Wlb;
        if (pass) __syncthreads();       // pass-0 reads done before restaging

        // stage A: 64 rows x 16 chunks(16B); swizzled LDS write
#pragma unroll
        for (int it = 0; it < 4; ++it) {
            int c = it * 256 + tid;
            int row = c >> 4, ci = c & 15;
            int gn = nb + row;
            short8 v = {};
            if (gn < Nn) v = *reinterpret_cast<const short8*>(A + (size_t)gn * D + ci * 8);
            *reinterpret_cast<short8*>(&Alds[row * D + ((ci ^ (row & 7)) * 8)]) = v;
        }
        // stage W: 128 rows x 16 chunks
#pragma unroll
        for (int it = 0; it < 8; ++it) {
            int c = it * 256 + tid;
            int j = c >> 4, ci = c & 15;
            short8 w = *reinterpret_cast<const short8*>(W + j * D + ci * 8);
            *reinterpret_cast<short8*>(&Blds[j * D + ((ci ^ (j & 7)) * 8)]) = w;
        }
        __syncthreads();

#pragma unroll
        for (int ks = 0; ks < 4; ++ks) {             // K chunks of 32
            const int kg = lane >> 4;                // k-group 0..3
            const int ci = ks * 4 + kg;
            short8 af[2], bfr[4];
#pragma unroll
            for (int bi = 0; bi < 2; ++bi) {
                int row = wr * 32 + bi * 16 + (lane & 15);
                af[bi] = *reinterpret_cast<const short8*>(
                    &Alds[row * D + ((ci ^ (row & 7)) * 8)]);
            }
#pragma unroll
            for (int ti = 0; ti < 4; ++ti) {
                int j = wc * 64 + ti * 16 + (lane & 15);
                bfr[ti] = *reinterpret_cast<const short8*>(
                    &Blds[j * D + ((ci ^ (j & 7)) * 8)]);
            }
#pragma unroll
            for (int bi = 0; bi < 2; ++bi)
#pragma unroll
                for (int ti = 0; ti < 4; ++ti)
                    acc[bi][ti] = __builtin_amdgcn_mfma_f32_16x16x32_bf16(
                        af[bi], bfr[ti], acc[bi][ti], 0, 0, 0);
        }
    }

    // epilogue: bias + BN fused per-column scale/shift; optional ReLU
#pragma unroll
    for (int ti = 0; ti < 4; ++ti) {
        int col = wc * 64 + ti * 16 + (lane & 15);
        float sc = gamma[col] * rsqrtf(rvar[col] + 1e-5f);
        float sh = bias[col] * sc + beta[col] - rmean[col] * sc;
#pragma unroll
        for (int bi = 0; bi < 2; ++bi) {
#pragma unroll
            for (int r = 0; r < 4; ++r) {
                int row = nb + wr * 32 + bi * 16 + (lane >> 4) * 4 + r;
                if (row < Nn) {
                    float v = acc[bi][ti][r] * sc + sh;
                    if (relu) v = fmaxf(v, 0.f);
                    if (out_bf16)
                        ((ushort*)outp)[(size_t)row * D + col] = (ushort)f2bf(v);
                    else
                        ((float*)outp)[(size_t)row * D + col] = v;
                }
            }
        }
    }
}

extern "C" void kernel_launch(void* const* d_in, const int* in_sizes, int n_in,
                              void* d_out, int out_size, void* d_ws, size_t ws_size,
                              hipStream_t stream)
{
    const float* x   = (const float*)d_in[0];
    const int*   ei  = (const int*)d_in[1];
    const float* Wl0 = (const float*)d_in[2];
    const float* Wr0 = (const float*)d_in[3];
    const float* b0  = (const float*)d_in[4];
    const float* g0  = (const float*)d_in[5];
    const float* be0 = (const float*)d_in[6];
    const float* rm0 = (const float*)d_in[7];
    const float* rv0 = (const float*)d_in[8];
    const float* Wl1 = (const float*)d_in[9];
    const float* Wr1 = (const float*)d_in[10];
    const float* b1  = (const float*)d_in[11];
    const float* g1  = (const float*)d_in[12];
    const float* be1 = (const float*)d_in[13];
    const float* rm1 = (const float*)d_in[14];
    const float* rv1 = (const float*)d_in[15];

    const int N = in_sizes[0] / D;
    const int E = in_sizes[1] / 2;
    const int* src = ei;
    const int* dst = ei + E;

    // workspace: xb u16[N*D] | aggb u16[N*D] | h0b u16[N*D] | wbf u16[4*16384] |
    //            head i[N] | nxt_src int2[E]
    ushort* xb   = (ushort*)d_ws;
    ushort* aggb = xb + (size_t)N * D;
    ushort* h0b  = aggb + (size_t)N * D;
    ushort* wbf  = h0b + (size_t)N * D;
    int*    head = (int*)(wbf + 4 * 16384);
    int2*   nxt_src = (int2*)(head + N);

    ushort* wl0b = wbf;
    ushort* wr0b = wbf + 16384;
    ushort* wl1b = wbf + 2 * 16384;
    ushort* wr1b = wbf + 3 * 16384;

    float* out = (float*)d_out;

    const int n4x = N * D / 4;
    const int CB  = (n4x + 16384 + 255) / 256;       // convert blocks
    const int EB  = (E + 255) / 256;                 // build blocks
    const int gemm_blocks = (N + BM - 1) / BM;
    const int gather_blocks = ((N + 3) / 4 * 64 + 255) / 256;   // 4 nodes per wave

    // ---- head = -1; then [convert || list-build] in one kernel ----
    hipMemsetAsync(head, 0xFF, sizeof(int) * N, stream);
    convert_build_kernel<<<CB + EB, 256, 0, stream>>>(
        x, xb, n4x, Wl0, Wr0, Wl1, Wr1, wbf, CB, src, dst, head, nxt_src, E);

    // ---- layer 0 ----
    gather_list_kernel<<<gather_blocks, 256, 0, stream>>>(xb, head, nxt_src, aggb, N);
    mfma_gemm_bn_kernel<<<gemm_blocks, 256, 0, stream>>>(
        aggb, xb, wl0b, wr0b, b0, g0, be0, rm0, rv0, h0b, 1, 1, N);
    // ---- layer 1 ----
    gather_list_kernel<<<gather_blocks, 256, 0, stream>>>(h0b, head, nxt_src, aggb, N);
    mfma_gemm_bn_kernel<<<gemm_blocks, 256, 0, stream>>>(
        aggb, h0b, wl1b, wr1b, b1, g1, be1, rm1, rv1, out, 0, 0, N);
}